// Round 1
// baseline (13361.913 us; speedup 1.0000x reference)
//
#include <hip/hip_runtime.h>
#include <hip/hip_bf16.h>
#include <math.h>

// ---------------- static config ----------------
// B=4, H=W=256, TIN=10, F=4, P=8, CIN=12, E=768, NB=8, BS=96,
// HP=WP=32, MID=3072, DEPTH=4, LAM=0.01, WF=17, TOK=4096, POS=B*32*17=2176

__device__ __forceinline__ float gelu_f(float v) {
    return 0.5f * v * (1.0f + erff(v * 0.70710678118654752f));
}
__device__ __forceinline__ float shrink_f(float v) {
    return (v > 0.01f) ? (v - 0.01f) : ((v < -0.01f) ? (v + 0.01f) : 0.0f);
}

#define STEP32 0.19634954084936207f  // 2*pi/32

// ---------------- patch embed ----------------
// t[b,hp,wp,e] = sum_{c,p,q} z[b,hp*8+p,wp*8+q,c] * conv_w[e,c,p,q] + conv_b[e] + pos_emb[hp,wp,e]
// grid: 256 blocks = b(4) * hp(32) * half(2); each block: 16 tokens (wp = half*16 .. +15)
__global__ __launch_bounds__(256) void patch_embed(
    const float* __restrict__ x, const float* __restrict__ grd,
    const float* __restrict__ conv_w, const float* __restrict__ conv_b,
    const float* __restrict__ pos_emb, float* __restrict__ t)
{
    __shared__ float lp[16 * 768];
    int bid = blockIdx.x;
    int half = bid & 1;
    int hp   = (bid >> 1) & 31;
    int b    = bid >> 6;
    int wp0  = half * 16;
    int tid  = threadIdx.x;

    for (int idx = tid; idx < 16 * 768; idx += 256) {
        int tok = idx / 768, j = idx % 768;
        int c = j >> 6, p = (j >> 3) & 7, q = j & 7;
        int hh = hp * 8 + p, ww = (wp0 + tok) * 8 + q;
        float v;
        if (c < 10) v = x[((b * 256 + hh) * 256 + ww) * 10 + c];
        else        v = grd[((b * 256 + hh) * 256 + ww) * 2 + (c - 10)];
        lp[idx] = v;
    }
    __syncthreads();

    for (int eo = 0; eo < 3; ++eo) {
        int e = eo * 256 + tid;
        float acc[16];
        #pragma unroll
        for (int i = 0; i < 16; ++i) acc[i] = 0.f;
        const float* wrow = conv_w + e * 768;
        for (int j = 0; j < 768; ++j) {
            float w = wrow[j];
            #pragma unroll
            for (int tok = 0; tok < 16; ++tok)
                acc[tok] += w * lp[tok * 768 + j];
        }
        float cb = conv_b[e];
        for (int tok = 0; tok < 16; ++tok) {
            int wp = wp0 + tok;
            t[((b * 32 + hp) * 32 + wp) * 768 + e] =
                acc[tok] + cb + pos_emb[(hp * 32 + wp) * 768 + e];
        }
    }
}

// ---------------- forward DFT along W (real -> 17 complex), scale 1/32 ----------------
// in: t (B,32,32,768); out: XW (B,32,17,768) as separate r/i planes
__global__ __launch_bounds__(256) void dft_fwd_w(const float* __restrict__ t,
        float* __restrict__ XWr, float* __restrict__ XWi)
{
    __shared__ float tile[32][256];
    __shared__ float c32[32], s32[32];
    int bh = blockIdx.x;            // b*32 + h
    int tid = threadIdx.x;
    if (tid < 32) { float a = tid * STEP32; c32[tid] = cosf(a); s32[tid] = sinf(a); }
    int c = blockIdx.y * 256 + tid;
    for (int w = 0; w < 32; ++w)
        tile[w][tid] = t[(bh * 32 + w) * 768 + c];
    __syncthreads();
    for (int kw = 0; kw <= 16; ++kw) {
        float ar = 0.f, ai = 0.f;
        for (int w = 0; w < 32; ++w) {
            int idx = (kw * w) & 31;
            float v = tile[w][tid];
            ar += v * c32[idx];
            ai -= v * s32[idx];
        }
        XWr[(bh * 17 + kw) * 768 + c] = ar * 0.03125f;
        XWi[(bh * 17 + kw) * 768 + c] = ai * 0.03125f;
    }
}

// ---------------- complex DFT along H (32 -> 32). INV=0: e^{-i}, INV=1: e^{+i} ----------------
// layout both ways: ((b*32 + h_or_kh)*17 + kw)*768 + c
template<int INV>
__global__ __launch_bounds__(128) void dft_h(const float* __restrict__ inR, const float* __restrict__ inI,
        float* __restrict__ outR, float* __restrict__ outI)
{
    __shared__ float colR[32][128], colI[32][128];
    __shared__ float c32[32], s32[32];
    int bk = blockIdx.x;            // b*17 + kw
    int b = bk / 17, kw = bk % 17;
    int tid = threadIdx.x;
    if (tid < 32) { float a = tid * STEP32; c32[tid] = cosf(a); s32[tid] = sinf(a); }
    int c = blockIdx.y * 128 + tid;
    for (int h = 0; h < 32; ++h) {
        colR[h][tid] = inR[((b * 32 + h) * 17 + kw) * 768 + c];
        colI[h][tid] = inI[((b * 32 + h) * 17 + kw) * 768 + c];
    }
    __syncthreads();
    for (int kh = 0; kh < 32; ++kh) {
        float ar = 0.f, ai = 0.f;
        for (int h = 0; h < 32; ++h) {
            int idx = (kh * h) & 31;
            float cr = colR[h][tid], ci = colI[h][tid];
            float cs = c32[idx], sn = s32[idx];
            if (INV) { ar += cr * cs - ci * sn; ai += ci * cs + cr * sn; }
            else     { ar += cr * cs + ci * sn; ai += ci * cs - cr * sn; }
        }
        outR[((b * 32 + kh) * 17 + kw) * 768 + c] = ar;
        outI[((b * 32 + kh) * 17 + kw) * 768 + c] = ai;
    }
}

// ---------------- inverse DFT along W (17 complex -> 32 real, hermitian) + residual ----------------
// x[w] = (1/32)[ Y0.r + (-1)^w Y16.r + sum_{k=1..15} 2(Yr cos - Yi sin) ] ; t += (in-place residual)
__global__ __launch_bounds__(256) void dft_inv_w(const float* __restrict__ YWr, const float* __restrict__ YWi,
        float* __restrict__ t)
{
    __shared__ float ldsR[17][256], ldsI[17][256];
    __shared__ float c32[32], s32[32];
    int bh = blockIdx.x;
    int tid = threadIdx.x;
    if (tid < 32) { float a = tid * STEP32; c32[tid] = cosf(a); s32[tid] = sinf(a); }
    int c = blockIdx.y * 256 + tid;
    for (int kw = 0; kw <= 16; ++kw) {
        ldsR[kw][tid] = YWr[(bh * 17 + kw) * 768 + c];
        ldsI[kw][tid] = YWi[(bh * 17 + kw) * 768 + c];
    }
    __syncthreads();
    for (int w = 0; w < 32; ++w) {
        float val = ldsR[0][tid] + ((w & 1) ? -ldsR[16][tid] : ldsR[16][tid]);
        for (int k = 1; k <= 15; ++k) {
            int idx = (k * w) & 31;
            val += 2.f * (ldsR[k][tid] * c32[idx] - ldsI[k][tid] * s32[idx]);
        }
        int gi = (bh * 32 + w) * 768 + c;
        t[gi] = val * 0.03125f + t[gi];
    }
}

// ---------------- spectral block-diag complex linear + activation ----------------
// out[pos, n*96+o] = act( sum_k inR*wR -/+ inI*wI + b )   (complex matvec, weights per block n)
// grid: (136 pos-chunks of 16, 8 blocks n); block = 192 threads = 2 positions x 96 outputs
// act: 0 = gelu, 1 = softshrink
__global__ __launch_bounds__(192) void spec_layer(const float* __restrict__ inR, const float* __restrict__ inI,
        const float* __restrict__ wR, const float* __restrict__ wI,
        const float* __restrict__ bR, const float* __restrict__ bI,
        float* __restrict__ outR, float* __restrict__ outI, int act)
{
    __shared__ float lx[16][2][96];      // 12.3 KB
    __shared__ float lwR[48 * 96];       // 18.4 KB (K-chunk of weights)
    __shared__ float lwI[48 * 96];       // 18.4 KB
    int n = blockIdx.y;
    int tid = threadIdx.x;
    int p2 = tid / 96, o = tid % 96;
    int pos0 = blockIdx.x * 16;

    for (int i = tid; i < 16 * 96; i += 192) {
        int pp = i / 96, k = i % 96;
        lx[pp][0][k] = inR[(pos0 + pp) * 768 + n * 96 + k];
        lx[pp][1][k] = inI[(pos0 + pp) * 768 + n * 96 + k];
    }
    float br = bR[n * 96 + o], bi = bI[n * 96 + o];
    float accr[8], acci[8];
    #pragma unroll
    for (int i = 0; i < 8; ++i) { accr[i] = br; acci[i] = bi; }

    for (int ch = 0; ch < 2; ++ch) {
        __syncthreads();
        for (int i = tid; i < 48 * 96; i += 192) {
            lwR[i] = wR[n * 9216 + ch * 4608 + i];
            lwI[i] = wI[n * 9216 + ch * 4608 + i];
        }
        __syncthreads();
        for (int pp = 0; pp < 8; ++pp) {
            const float* xr = lx[pp * 2 + p2][0];
            const float* xi = lx[pp * 2 + p2][1];
            float ar = accr[pp], ai = acci[pp];
            #pragma unroll 4
            for (int k = 0; k < 48; ++k) {
                float wr = lwR[k * 96 + o], wi = lwI[k * 96 + o];
                float xrk = xr[ch * 48 + k], xik = xi[ch * 48 + k];
                ar += xrk * wr - xik * wi;
                ai += xik * wr + xrk * wi;
            }
            accr[pp] = ar; acci[pp] = ai;
        }
    }
    for (int pp = 0; pp < 8; ++pp) {
        int pos = pos0 + pp * 2 + p2;
        float ar = accr[pp], ai = acci[pp];
        if (act == 0) { ar = gelu_f(ar); ai = gelu_f(ai); }
        else          { ar = shrink_f(ar); ai = shrink_f(ai); }
        outR[pos * 768 + n * 96 + o] = ar;
        outI[pos * 768 + n * 96 + o] = ai;
    }
}

// ---------------- fp32 tiled GEMM: C = act(A[M,K] @ W[K,N] + bias[N]) ----------------
// 64x64 tile, k-tile 16, 256 threads, 4x4 microtile. M,N mult of 64; K mult of 16.
template<int ACT>
__global__ __launch_bounds__(256) void gemm_bias(const float* __restrict__ A,
        const float* __restrict__ W, const float* __restrict__ bias,
        float* __restrict__ C, int M, int N, int K)
{
    __shared__ float As[16][68];
    __shared__ float Bs[16][68];
    const int tid = threadIdx.x;
    const int tx = tid & 15, ty = tid >> 4;
    const int row0 = blockIdx.y * 64, col0 = blockIdx.x * 64;
    const int ar = tid >> 2;          // 0..63  (A row in tile)
    const int ak = (tid & 3) * 4;     // 0,4,8,12 (A k-offset)
    const int bk = tid >> 4;          // 0..15 (W k in tile)
    const int bc = (tid & 15) * 4;    // 0..60 (W col offset)
    float acc[4][4] = {};

    for (int k0 = 0; k0 < K; k0 += 16) {
        float4 va = *(const float4*)&A[(row0 + ar) * K + k0 + ak];
        float4 vb = *(const float4*)&W[(k0 + bk) * N + col0 + bc];
        __syncthreads();
        As[ak + 0][ar] = va.x;
        As[ak + 1][ar] = va.y;
        As[ak + 2][ar] = va.z;
        As[ak + 3][ar] = va.w;
        *(float4*)&Bs[bk][bc] = vb;
        __syncthreads();
        #pragma unroll
        for (int kk = 0; kk < 16; ++kk) {
            float4 a = *(const float4*)&As[kk][ty * 4];
            float4 b = *(const float4*)&Bs[kk][tx * 4];
            acc[0][0] += a.x * b.x; acc[0][1] += a.x * b.y; acc[0][2] += a.x * b.z; acc[0][3] += a.x * b.w;
            acc[1][0] += a.y * b.x; acc[1][1] += a.y * b.y; acc[1][2] += a.y * b.z; acc[1][3] += a.y * b.w;
            acc[2][0] += a.z * b.x; acc[2][1] += a.z * b.y; acc[2][2] += a.z * b.z; acc[2][3] += a.z * b.w;
            acc[3][0] += a.w * b.x; acc[3][1] += a.w * b.y; acc[3][2] += a.w * b.z; acc[3][3] += a.w * b.w;
        }
    }
    float bv[4];
    #pragma unroll
    for (int j = 0; j < 4; ++j) bv[j] = bias[col0 + tx * 4 + j];
    #pragma unroll
    for (int i = 0; i < 4; ++i) {
        float r[4];
        #pragma unroll
        for (int j = 0; j < 4; ++j) {
            r[j] = acc[i][j] + bv[j];
            if (ACT) r[j] = gelu_f(r[j]);
        }
        float4 v = make_float4(r[0], r[1], r[2], r[3]);
        *(float4*)&C[(row0 + ty * 4 + i) * N + col0 + tx * 4] = v;
    }
}

// ---------------- head output scatter (pixel shuffle) ----------------
// out[b, hp*8+p, wp*8+q, f] = h2[((b*32+hp)*32+wp)*64 + p*8+q]
__global__ __launch_bounds__(256) void scatter_head(const float* __restrict__ h2,
        float* __restrict__ out, int f)
{
    int idx = blockIdx.x * 256 + threadIdx.x;     // 0 .. 262143
    int pq  = idx & 63;
    int tok = idx >> 6;
    int wp  = tok & 31;
    int hp  = (tok >> 5) & 31;
    int b   = tok >> 10;
    int p = pq >> 3, q = pq & 7;
    out[((b * 256 + hp * 8 + p) * 256 + wp * 8 + q) * 4 + f] = h2[idx];
}

// ---------------- launch ----------------
extern "C" void kernel_launch(void* const* d_in, const int* in_sizes, int n_in,
                              void* d_out, int out_size, void* d_ws, size_t ws_size,
                              hipStream_t stream) {
    const float* x        = (const float*)d_in[0];
    const float* grd      = (const float*)d_in[1];
    const float* conv_w   = (const float*)d_in[2];
    const float* conv_b   = (const float*)d_in[3];
    const float* pos_emb  = (const float*)d_in[4];
    const float* w1       = (const float*)d_in[5];
    const float* b1       = (const float*)d_in[6];
    const float* w2       = (const float*)d_in[7];
    const float* b2       = (const float*)d_in[8];
    const float* fc1_w    = (const float*)d_in[9];
    const float* fc1_b    = (const float*)d_in[10];
    const float* fc2_w    = (const float*)d_in[11];
    const float* fc2_b    = (const float*)d_in[12];
    const float* head_w1  = (const float*)d_in[13];
    const float* head_b1  = (const float*)d_in[14];
    const float* head_w2  = (const float*)d_in[15];
    const float* head_b2  = (const float*)d_in[16];
    float* out = (float*)d_out;
    float* ws  = (float*)d_ws;

    // workspace layout (floats)
    float* t   = ws;                    // 4096*768          = 3,145,728
    float* xr  = t   + 3145728;         // 2176*768          = 1,671,168
    float* xi  = xr  + 1671168;
    float* o1r = xi  + 1671168;
    float* o1i = o1r + 1671168;
    float* hid = o1i + 1671168;         // 4096*3072         = 12,582,912
    float* h2  = hid + 12582912;        // 4096*64           = 262,144
    // total = 22,675,456 floats = 90.7 MB

    patch_embed<<<dim3(256), 256, 0, stream>>>(x, grd, conv_w, conv_b, pos_emb, t);

    for (int f = 0; f < 4; ++f) {
        for (int d = 0; d < 4; ++d) {
            // rfft2 (ortho, 1/32 folded into fwd-W pass)
            dft_fwd_w<<<dim3(128, 3), 256, 0, stream>>>(t, o1r, o1i);
            dft_h<0><<<dim3(68, 6), 128, 0, stream>>>(o1r, o1i, xr, xi);
            // block-diag complex MLP
            spec_layer<<<dim3(136, 8), 192, 0, stream>>>(
                xr, xi, w1 + d * 147456, w1 + d * 147456 + 73728,
                b1 + d * 1536, b1 + d * 1536 + 768, o1r, o1i, 0);
            spec_layer<<<dim3(136, 8), 192, 0, stream>>>(
                o1r, o1i, w2 + d * 147456, w2 + d * 147456 + 73728,
                b2 + d * 1536, b2 + d * 1536 + 768, xr, xi, 1);
            // irfft2 + residual (1/32 folded into inv-W pass)
            dft_h<1><<<dim3(68, 6), 128, 0, stream>>>(xr, xi, o1r, o1i);
            dft_inv_w<<<dim3(128, 3), 256, 0, stream>>>(o1r, o1i, t);
            // channel MLP 768 -> 3072 -> 768 (replaces t)
            gemm_bias<1><<<dim3(48, 64), 256, 0, stream>>>(
                t, fc1_w + d * 2359296, fc1_b + d * 3072, hid, 4096, 3072, 768);
            gemm_bias<0><<<dim3(12, 64), 256, 0, stream>>>(
                hid, fc2_w + d * 2359296, fc2_b + d * 768, t, 4096, 768, 3072);
        }
        // head on current state (does not modify t)
        gemm_bias<1><<<dim3(24, 64), 256, 0, stream>>>(
            t, head_w1, head_b1, hid, 4096, 1536, 768);
        gemm_bias<0><<<dim3(1, 64), 256, 0, stream>>>(
            hid, head_w2, head_b2, h2, 4096, 64, 1536);
        scatter_head<<<dim3(1024), 256, 0, stream>>>(h2, out, f);
    }
}

// Round 2
// 6551.698 us; speedup vs baseline: 2.0395x; 2.0395x over previous
//
#include <hip/hip_runtime.h>
#include <hip/hip_bf16.h>
#include <math.h>

// ---------------- static config ----------------
// B=4, H=W=256, TIN=10, F=4, P=8, CIN=12, E=768, NB=8, BS=96,
// HP=WP=32, MID=3072, DEPTH=4, LAM=0.01, WF=17, TOK=4096, POS=B*32*17=2176

typedef __attribute__((ext_vector_type(8))) _Float16 half8;
typedef __attribute__((ext_vector_type(4))) _Float16 half4v;
typedef __attribute__((ext_vector_type(4))) float float4v;

__device__ __forceinline__ float gelu_f(float v) {
    return 0.5f * v * (1.0f + erff(v * 0.70710678118654752f));
}
__device__ __forceinline__ float shrink_f(float v) {
    return (v > 0.01f) ? (v - 0.01f) : ((v < -0.01f) ? (v + 0.01f) : 0.0f);
}

#define STEP32 0.19634954084936207f  // 2*pi/32

// async 16B global->LDS (lds dest must be wave-uniform; HW adds lane*16)
__device__ __forceinline__ void async16(const void* g, void* l) {
    __builtin_amdgcn_global_load_lds(
        (const __attribute__((address_space(1))) unsigned int*)g,
        (__attribute__((address_space(3))) unsigned int*)l, 16, 0, 0);
}

// ---------------- patch embed ----------------
__global__ __launch_bounds__(256) void patch_embed(
    const float* __restrict__ x, const float* __restrict__ grd,
    const float* __restrict__ conv_w, const float* __restrict__ conv_b,
    const float* __restrict__ pos_emb, float* __restrict__ t)
{
    __shared__ float lp[16 * 768];
    int bid = blockIdx.x;
    int half = bid & 1;
    int hp   = (bid >> 1) & 31;
    int b    = bid >> 6;
    int wp0  = half * 16;
    int tid  = threadIdx.x;

    for (int idx = tid; idx < 16 * 768; idx += 256) {
        int tok = idx / 768, j = idx % 768;
        int c = j >> 6, p = (j >> 3) & 7, q = j & 7;
        int hh = hp * 8 + p, ww = (wp0 + tok) * 8 + q;
        float v;
        if (c < 10) v = x[((b * 256 + hh) * 256 + ww) * 10 + c];
        else        v = grd[((b * 256 + hh) * 256 + ww) * 2 + (c - 10)];
        lp[idx] = v;
    }
    __syncthreads();

    for (int eo = 0; eo < 3; ++eo) {
        int e = eo * 256 + tid;
        float acc[16];
        #pragma unroll
        for (int i = 0; i < 16; ++i) acc[i] = 0.f;
        const float* wrow = conv_w + e * 768;
        for (int j = 0; j < 768; ++j) {
            float w = wrow[j];
            #pragma unroll
            for (int tok = 0; tok < 16; ++tok)
                acc[tok] += w * lp[tok * 768 + j];
        }
        float cb = conv_b[e];
        for (int tok = 0; tok < 16; ++tok) {
            int wp = wp0 + tok;
            t[((b * 32 + hp) * 32 + wp) * 768 + e] =
                acc[tok] + cb + pos_emb[(hp * 32 + wp) * 768 + e];
        }
    }
}

// ---------------- forward DFT along W (real -> 17 complex), scale 1/32 ----------------
__global__ __launch_bounds__(256) void dft_fwd_w(const float* __restrict__ t,
        float* __restrict__ XWr, float* __restrict__ XWi)
{
    __shared__ float tile[32][256];
    __shared__ float c32[32], s32[32];
    int bh = blockIdx.x;            // b*32 + h
    int tid = threadIdx.x;
    if (tid < 32) { float a = tid * STEP32; c32[tid] = cosf(a); s32[tid] = sinf(a); }
    int c = blockIdx.y * 256 + tid;
    for (int w = 0; w < 32; ++w)
        tile[w][tid] = t[(bh * 32 + w) * 768 + c];
    __syncthreads();
    for (int kw = 0; kw <= 16; ++kw) {
        float ar = 0.f, ai = 0.f;
        for (int w = 0; w < 32; ++w) {
            int idx = (kw * w) & 31;
            float v = tile[w][tid];
            ar += v * c32[idx];
            ai -= v * s32[idx];
        }
        XWr[(bh * 17 + kw) * 768 + c] = ar * 0.03125f;
        XWi[(bh * 17 + kw) * 768 + c] = ai * 0.03125f;
    }
}

// ---------------- complex DFT along H ----------------
template<int INV>
__global__ __launch_bounds__(128) void dft_h(const float* __restrict__ inR, const float* __restrict__ inI,
        float* __restrict__ outR, float* __restrict__ outI)
{
    __shared__ float colR[32][128], colI[32][128];
    __shared__ float c32[32], s32[32];
    int bk = blockIdx.x;            // b*17 + kw
    int b = bk / 17, kw = bk % 17;
    int tid = threadIdx.x;
    if (tid < 32) { float a = tid * STEP32; c32[tid] = cosf(a); s32[tid] = sinf(a); }
    int c = blockIdx.y * 128 + tid;
    for (int h = 0; h < 32; ++h) {
        colR[h][tid] = inR[((b * 32 + h) * 17 + kw) * 768 + c];
        colI[h][tid] = inI[((b * 32 + h) * 17 + kw) * 768 + c];
    }
    __syncthreads();
    for (int kh = 0; kh < 32; ++kh) {
        float ar = 0.f, ai = 0.f;
        for (int h = 0; h < 32; ++h) {
            int idx = (kh * h) & 31;
            float cr = colR[h][tid], ci = colI[h][tid];
            float cs = c32[idx], sn = s32[idx];
            if (INV) { ar += cr * cs - ci * sn; ai += ci * cs + cr * sn; }
            else     { ar += cr * cs + ci * sn; ai += ci * cs - cr * sn; }
        }
        outR[((b * 32 + kh) * 17 + kw) * 768 + c] = ar;
        outI[((b * 32 + kh) * 17 + kw) * 768 + c] = ai;
    }
}

// ---------------- inverse DFT along W + residual ----------------
__global__ __launch_bounds__(256) void dft_inv_w(const float* __restrict__ YWr, const float* __restrict__ YWi,
        float* __restrict__ t)
{
    __shared__ float ldsR[17][256], ldsI[17][256];
    __shared__ float c32[32], s32[32];
    int bh = blockIdx.x;
    int tid = threadIdx.x;
    if (tid < 32) { float a = tid * STEP32; c32[tid] = cosf(a); s32[tid] = sinf(a); }
    int c = blockIdx.y * 256 + tid;
    for (int kw = 0; kw <= 16; ++kw) {
        ldsR[kw][tid] = YWr[(bh * 17 + kw) * 768 + c];
        ldsI[kw][tid] = YWi[(bh * 17 + kw) * 768 + c];
    }
    __syncthreads();
    for (int w = 0; w < 32; ++w) {
        float val = ldsR[0][tid] + ((w & 1) ? -ldsR[16][tid] : ldsR[16][tid]);
        for (int k = 1; k <= 15; ++k) {
            int idx = (k * w) & 31;
            val += 2.f * (ldsR[k][tid] * c32[idx] - ldsI[k][tid] * s32[idx]);
        }
        int gi = (bh * 32 + w) * 768 + c;
        t[gi] = val * 0.03125f + t[gi];
    }
}

// ---------------- spectral block-diag complex linear + activation ----------------
__global__ __launch_bounds__(192) void spec_layer(const float* __restrict__ inR, const float* __restrict__ inI,
        const float* __restrict__ wR, const float* __restrict__ wI,
        const float* __restrict__ bR, const float* __restrict__ bI,
        float* __restrict__ outR, float* __restrict__ outI, int act)
{
    __shared__ float lx[16][2][96];
    __shared__ float lwR[48 * 96];
    __shared__ float lwI[48 * 96];
    int n = blockIdx.y;
    int tid = threadIdx.x;
    int p2 = tid / 96, o = tid % 96;
    int pos0 = blockIdx.x * 16;

    for (int i = tid; i < 16 * 96; i += 192) {
        int pp = i / 96, k = i % 96;
        lx[pp][0][k] = inR[(pos0 + pp) * 768 + n * 96 + k];
        lx[pp][1][k] = inI[(pos0 + pp) * 768 + n * 96 + k];
    }
    float br = bR[n * 96 + o], bi = bI[n * 96 + o];
    float accr[8], acci[8];
    #pragma unroll
    for (int i = 0; i < 8; ++i) { accr[i] = br; acci[i] = bi; }

    for (int ch = 0; ch < 2; ++ch) {
        __syncthreads();
        for (int i = tid; i < 48 * 96; i += 192) {
            lwR[i] = wR[n * 9216 + ch * 4608 + i];
            lwI[i] = wI[n * 9216 + ch * 4608 + i];
        }
        __syncthreads();
        for (int pp = 0; pp < 8; ++pp) {
            const float* xr = lx[pp * 2 + p2][0];
            const float* xi = lx[pp * 2 + p2][1];
            float ar = accr[pp], ai = acci[pp];
            #pragma unroll 4
            for (int k = 0; k < 48; ++k) {
                float wr = lwR[k * 96 + o], wi = lwI[k * 96 + o];
                float xrk = xr[ch * 48 + k], xik = xi[ch * 48 + k];
                ar += xrk * wr - xik * wi;
                ai += xik * wr + xrk * wi;
            }
            accr[pp] = ar; acci[pp] = ai;
        }
    }
    for (int pp = 0; pp < 8; ++pp) {
        int pos = pos0 + pp * 2 + p2;
        float ar = accr[pp], ai = acci[pp];
        if (act == 0) { ar = gelu_f(ar); ai = gelu_f(ai); }
        else          { ar = shrink_f(ar); ai = shrink_f(ai); }
        outR[pos * 768 + n * 96 + o] = ar;
        outI[pos * 768 + n * 96 + o] = ai;
    }
}

// ---------------- f32 -> f16 elementwise (vectorized x4) ----------------
__global__ __launch_bounds__(256) void cvt_f16(const float* __restrict__ in,
        _Float16* __restrict__ out)
{
    int i = blockIdx.x * 256 + threadIdx.x;
    float4 v = ((const float4*)in)[i];
    half4v o;
    o.x = (_Float16)v.x; o.y = (_Float16)v.y; o.z = (_Float16)v.z; o.w = (_Float16)v.w;
    ((half4v*)out)[i] = o;
}

// ---------------- f32 [K][N] -> f16 [N][K] transpose ----------------
__global__ __launch_bounds__(256) void cvt_transpose(const float* __restrict__ in,
        _Float16* __restrict__ out, int K, int N)
{
    __shared__ float tile[32][33];
    int kb = blockIdx.x * 32, nb = blockIdx.y * 32;
    int tx = threadIdx.x & 31, ty = threadIdx.x >> 5;   // ty 0..7
    #pragma unroll
    for (int r = 0; r < 32; r += 8)
        tile[ty + r][tx] = in[(size_t)(kb + ty + r) * N + nb + tx];
    __syncthreads();
    #pragma unroll
    for (int r = 0; r < 32; r += 8)
        out[(size_t)(nb + ty + r) * K + kb + tx] = (_Float16)tile[tx][ty + r];
}

// ---------------- fp16 MFMA GEMM: C = act(A[M,K] @ Bt[N,K]^T + bias) ----------------
// BM=128, BK=32, 256 threads = 4 waves (2x2), wave tile 64 x BN/2.
// A row-major [M][K] f16; Bt row-major [N][K] f16 (pre-transposed weights).
// OUT_F16: write _Float16, else float. ACT: gelu.
template<int BN, int OUT_F16, int ACT>
__global__ __launch_bounds__(256) void gemm_h(const _Float16* __restrict__ A,
        const _Float16* __restrict__ Bt, const float* __restrict__ bias,
        void* __restrict__ Cout, int M, int N, int K)
{
    constexpr int WN  = BN / 2;      // wave cols
    constexpr int FN  = WN / 16;     // col frags per wave
    constexpr int NBJ = BN / 64;     // B staging rounds
    __shared__ _Float16 Al[128 * 32];
    __shared__ _Float16 Bl[BN * 32];

    const int tid  = threadIdx.x;
    const int wave = tid >> 6;
    const int lane = tid & 63;
    const int wr   = wave >> 1;      // 0..1
    const int wc   = wave & 1;       // 0..1
    const int lr   = lane & 15;
    const int quad = lane >> 4;
    const int row0 = blockIdx.y * 128;
    const int col0 = blockIdx.x * BN;

    // staging addresses: lane covers row (lane>>2), k-chunk (lane&3)*8
    const int srow = lane >> 2;
    const int skof = (lane & 3) * 8;

    float4v acc[4][FN];
    #pragma unroll
    for (int i = 0; i < 4; ++i)
        #pragma unroll
        for (int j = 0; j < FN; ++j) {
            float4v z = {0.f, 0.f, 0.f, 0.f};
            acc[i][j] = z;
        }

    for (int k0 = 0; k0 < K; k0 += 32) {
        __syncthreads();
        #pragma unroll
        for (int j = 0; j < 2; ++j)
            async16(A + (size_t)(row0 + j * 64 + wave * 16 + srow) * K + k0 + skof,
                    &Al[(j * 64 + wave * 16) * 32]);
        #pragma unroll
        for (int j = 0; j < NBJ; ++j)
            async16(Bt + (size_t)(col0 + j * 64 + wave * 16 + srow) * K + k0 + skof,
                    &Bl[(j * 64 + wave * 16) * 32]);
        __syncthreads();

        half8 af[4], bf[FN];
        #pragma unroll
        for (int i = 0; i < 4; ++i)
            af[i] = *(const half8*)&Al[(wr * 64 + i * 16 + lr) * 32 + quad * 8];
        #pragma unroll
        for (int j = 0; j < FN; ++j)
            bf[j] = *(const half8*)&Bl[(wc * WN + j * 16 + lr) * 32 + quad * 8];
        #pragma unroll
        for (int i = 0; i < 4; ++i)
            #pragma unroll
            for (int j = 0; j < FN; ++j)
                acc[i][j] = __builtin_amdgcn_mfma_f32_16x16x32_f16(af[i], bf[j], acc[i][j], 0, 0, 0);
    }

    #pragma unroll
    for (int j = 0; j < FN; ++j) {
        int col = col0 + wc * WN + j * 16 + lr;
        float bj = bias[col];
        #pragma unroll
        for (int i = 0; i < 4; ++i) {
            int row = row0 + wr * 64 + i * 16 + quad * 4;
            #pragma unroll
            for (int r = 0; r < 4; ++r) {
                float v = acc[i][j][r] + bj;
                if (ACT) v = gelu_f(v);
                if (OUT_F16) ((_Float16*)Cout)[(size_t)(row + r) * N + col] = (_Float16)v;
                else         ((float*)Cout)[(size_t)(row + r) * N + col] = v;
            }
        }
    }
}

// ---------------- head output scatter (pixel shuffle) ----------------
__global__ __launch_bounds__(256) void scatter_head(const float* __restrict__ h2,
        float* __restrict__ out, int f)
{
    int idx = blockIdx.x * 256 + threadIdx.x;     // 0 .. 262143
    int pq  = idx & 63;
    int tok = idx >> 6;
    int wp  = tok & 31;
    int hp  = (tok >> 5) & 31;
    int b   = tok >> 10;
    int p = pq >> 3, q = pq & 7;
    out[((b * 256 + hp * 8 + p) * 256 + wp * 8 + q) * 4 + f] = h2[idx];
}

// ---------------- launch ----------------
extern "C" void kernel_launch(void* const* d_in, const int* in_sizes, int n_in,
                              void* d_out, int out_size, void* d_ws, size_t ws_size,
                              hipStream_t stream) {
    const float* x        = (const float*)d_in[0];
    const float* grd      = (const float*)d_in[1];
    const float* conv_w   = (const float*)d_in[2];
    const float* conv_b   = (const float*)d_in[3];
    const float* pos_emb  = (const float*)d_in[4];
    const float* w1       = (const float*)d_in[5];
    const float* b1       = (const float*)d_in[6];
    const float* w2       = (const float*)d_in[7];
    const float* b2       = (const float*)d_in[8];
    const float* fc1_w    = (const float*)d_in[9];
    const float* fc1_b    = (const float*)d_in[10];
    const float* fc2_w    = (const float*)d_in[11];
    const float* fc2_b    = (const float*)d_in[12];
    const float* head_w1  = (const float*)d_in[13];
    const float* head_b1  = (const float*)d_in[14];
    const float* head_w2  = (const float*)d_in[15];
    const float* head_b2  = (const float*)d_in[16];
    float* out = (float*)d_out;
    float* ws  = (float*)d_ws;

    // workspace layout (float units)
    float* t    = ws;                       // 3,145,728
    float* xr   = t    + 3145728;           // 1,671,168
    float* xi   = xr   + 1671168;
    float* o1r  = xi   + 1671168;
    float* o1i  = o1r  + 1671168;
    float* h2   = o1i  + 1671168;           // 262,144
    _Float16* t_h   = (_Float16*)(h2 + 262144);          // 3,145,728 halfs = 1,572,864 f
    _Float16* hid_h = (_Float16*)(h2 + 262144 + 1572864); // 12,582,912 halfs = 6,291,456 f
    _Float16* Wt    = (_Float16*)(h2 + 262144 + 1572864 + 6291456); // 2,359,296 halfs
    // total = 19,136,512 floats = 76.5 MB

    patch_embed<<<dim3(256), 256, 0, stream>>>(x, grd, conv_w, conv_b, pos_emb, t);

    for (int f = 0; f < 4; ++f) {
        for (int d = 0; d < 4; ++d) {
            // rfft2 (ortho, 1/32 folded into fwd-W pass)
            dft_fwd_w<<<dim3(128, 3), 256, 0, stream>>>(t, o1r, o1i);
            dft_h<0><<<dim3(68, 6), 128, 0, stream>>>(o1r, o1i, xr, xi);
            spec_layer<<<dim3(136, 8), 192, 0, stream>>>(
                xr, xi, w1 + d * 147456, w1 + d * 147456 + 73728,
                b1 + d * 1536, b1 + d * 1536 + 768, o1r, o1i, 0);
            spec_layer<<<dim3(136, 8), 192, 0, stream>>>(
                o1r, o1i, w2 + d * 147456, w2 + d * 147456 + 73728,
                b2 + d * 1536, b2 + d * 1536 + 768, xr, xi, 1);
            dft_h<1><<<dim3(68, 6), 128, 0, stream>>>(xr, xi, o1r, o1i);
            dft_inv_w<<<dim3(128, 3), 256, 0, stream>>>(o1r, o1i, t);

            // channel MLP 768 -> 3072 -> 768 via fp16 MFMA
            cvt_f16<<<dim3(3072), 256, 0, stream>>>(t, t_h);
            cvt_transpose<<<dim3(24, 96), 256, 0, stream>>>(fc1_w + (size_t)d * 2359296, Wt, 768, 3072);
            gemm_h<128, 1, 1><<<dim3(24, 32), 256, 0, stream>>>(
                t_h, Wt, fc1_b + d * 3072, hid_h, 4096, 3072, 768);
            cvt_transpose<<<dim3(96, 24), 256, 0, stream>>>(fc2_w + (size_t)d * 2359296, Wt, 3072, 768);
            gemm_h<64, 0, 0><<<dim3(12, 32), 256, 0, stream>>>(
                hid_h, Wt, fc2_b + d * 768, t, 4096, 768, 3072);
        }
        // head on current state (does not modify t)
        cvt_f16<<<dim3(3072), 256, 0, stream>>>(t, t_h);
        cvt_transpose<<<dim3(24, 48), 256, 0, stream>>>(head_w1, Wt, 768, 1536);
        gemm_h<128, 1, 1><<<dim3(12, 32), 256, 0, stream>>>(
            t_h, Wt, head_b1, hid_h, 4096, 1536, 768);
        cvt_transpose<<<dim3(48, 2), 256, 0, stream>>>(head_w2, Wt, 1536, 64);
        gemm_h<64, 0, 0><<<dim3(1, 32), 256, 0, stream>>>(
            hid_h, Wt, head_b2, h2, 4096, 64, 1536);
        scatter_head<<<dim3(1024), 256, 0, stream>>>(h2, out, f);
    }
}

// Round 3
// 4508.905 us; speedup vs baseline: 2.9634x; 1.4531x over previous
//
#include <hip/hip_runtime.h>
#include <hip/hip_bf16.h>
#include <math.h>

// ---------------- static config ----------------
// B=4, H=W=256, TIN=10, F=4, P=8, CIN=12, E=768, NB=8, BS=96,
// HP=WP=32, MID=3072, DEPTH=4, LAM=0.01, WF=17, TOK=4096, POS=B*32*17=2176

typedef __attribute__((ext_vector_type(8))) _Float16 half8;
typedef __attribute__((ext_vector_type(4))) _Float16 half4v;
typedef __attribute__((ext_vector_type(4))) float float4v;

__device__ __forceinline__ float gelu_f(float v) {
    return 0.5f * v * (1.0f + erff(v * 0.70710678118654752f));
}
__device__ __forceinline__ float shrink_f(float v) {
    return (v > 0.01f) ? (v - 0.01f) : ((v < -0.01f) ? (v + 0.01f) : 0.0f);
}

#define STEP32 0.19634954084936207f  // 2*pi/32

// async 16B global->LDS (lds dest wave-uniform; HW adds lane*16)
__device__ __forceinline__ void async16(const void* g, void* l) {
    __builtin_amdgcn_global_load_lds(
        (const __attribute__((address_space(1))) unsigned int*)g,
        (__attribute__((address_space(3))) unsigned int*)l, 16, 0, 0);
}

__device__ __forceinline__ half8 ld_f32x8_as_h8(const float* p) {
    float4 u = *(const float4*)p;
    float4 v = *(const float4*)(p + 4);
    half8 h;
    h[0] = (_Float16)u.x; h[1] = (_Float16)u.y; h[2] = (_Float16)u.z; h[3] = (_Float16)u.w;
    h[4] = (_Float16)v.x; h[5] = (_Float16)v.y; h[6] = (_Float16)v.z; h[7] = (_Float16)v.w;
    return h;
}

// ---------------- gather patches into A_h [4096][768] f16 ----------------
// A[tok][c*64+p*8+q] = (c<10 ? x[b,hp*8+p,wp*8+q,c] : grid[...,c-10])
__global__ __launch_bounds__(256) void gather_patch(const float* __restrict__ x,
        const float* __restrict__ grd, _Float16* __restrict__ A)
{
    int idx = blockIdx.x * 256 + threadIdx.x;     // 0 .. 3,145,727
    int j   = idx % 768;
    int tok = idx / 768;
    int c = j >> 6, p = (j >> 3) & 7, q = j & 7;
    int wp = tok & 31, hp = (tok >> 5) & 31, b = tok >> 10;
    int hh = hp * 8 + p, ww = wp * 8 + q;
    float v;
    if (c < 10) v = x[((b * 256 + hh) * 256 + ww) * 10 + c];
    else        v = grd[((b * 256 + hh) * 256 + ww) * 2 + (c - 10)];
    A[idx] = (_Float16)v;
}

// ---------------- forward DFT along W (real -> 17 complex), scale 1/32 ----------------
__global__ __launch_bounds__(256) void dft_fwd_w(const float* __restrict__ t,
        float* __restrict__ XWr, float* __restrict__ XWi)
{
    __shared__ float tile[32][256];
    __shared__ float c32[32], s32[32];
    int bh = blockIdx.x;            // b*32 + h
    int tid = threadIdx.x;
    if (tid < 32) { float a = tid * STEP32; c32[tid] = cosf(a); s32[tid] = sinf(a); }
    int c = blockIdx.y * 256 + tid;
    for (int w = 0; w < 32; ++w)
        tile[w][tid] = t[(bh * 32 + w) * 768 + c];
    __syncthreads();
    for (int kw = 0; kw <= 16; ++kw) {
        float ar = 0.f, ai = 0.f;
        for (int w = 0; w < 32; ++w) {
            int idx = (kw * w) & 31;
            float v = tile[w][tid];
            ar += v * c32[idx];
            ai -= v * s32[idx];
        }
        XWr[(bh * 17 + kw) * 768 + c] = ar * 0.03125f;
        XWi[(bh * 17 + kw) * 768 + c] = ai * 0.03125f;
    }
}

// ---------------- complex DFT along H ----------------
template<int INV>
__global__ __launch_bounds__(128) void dft_h(const float* __restrict__ inR, const float* __restrict__ inI,
        float* __restrict__ outR, float* __restrict__ outI)
{
    __shared__ float colR[32][128], colI[32][128];
    __shared__ float c32[32], s32[32];
    int bk = blockIdx.x;            // b*17 + kw
    int b = bk / 17, kw = bk % 17;
    int tid = threadIdx.x;
    if (tid < 32) { float a = tid * STEP32; c32[tid] = cosf(a); s32[tid] = sinf(a); }
    int c = blockIdx.y * 128 + tid;
    for (int h = 0; h < 32; ++h) {
        colR[h][tid] = inR[((b * 32 + h) * 17 + kw) * 768 + c];
        colI[h][tid] = inI[((b * 32 + h) * 17 + kw) * 768 + c];
    }
    __syncthreads();
    for (int kh = 0; kh < 32; ++kh) {
        float ar = 0.f, ai = 0.f;
        for (int h = 0; h < 32; ++h) {
            int idx = (kh * h) & 31;
            float cr = colR[h][tid], ci = colI[h][tid];
            float cs = c32[idx], sn = s32[idx];
            if (INV) { ar += cr * cs - ci * sn; ai += ci * cs + cr * sn; }
            else     { ar += cr * cs + ci * sn; ai += ci * cs - cr * sn; }
        }
        outR[((b * 32 + kh) * 17 + kw) * 768 + c] = ar;
        outI[((b * 32 + kh) * 17 + kw) * 768 + c] = ai;
    }
}

// ---------------- inverse DFT along W + residual; dual fp32/f16 write ----------------
__global__ __launch_bounds__(256) void dft_inv_w(const float* __restrict__ YWr, const float* __restrict__ YWi,
        float* __restrict__ t, _Float16* __restrict__ t_h)
{
    __shared__ float ldsR[17][256], ldsI[17][256];
    __shared__ float c32[32], s32[32];
    int bh = blockIdx.x;
    int tid = threadIdx.x;
    if (tid < 32) { float a = tid * STEP32; c32[tid] = cosf(a); s32[tid] = sinf(a); }
    int c = blockIdx.y * 256 + tid;
    for (int kw = 0; kw <= 16; ++kw) {
        ldsR[kw][tid] = YWr[(bh * 17 + kw) * 768 + c];
        ldsI[kw][tid] = YWi[(bh * 17 + kw) * 768 + c];
    }
    __syncthreads();
    for (int w = 0; w < 32; ++w) {
        float val = ldsR[0][tid] + ((w & 1) ? -ldsR[16][tid] : ldsR[16][tid]);
        for (int k = 1; k <= 15; ++k) {
            int idx = (k * w) & 31;
            val += 2.f * (ldsR[k][tid] * c32[idx] - ldsI[k][tid] * s32[idx]);
        }
        int gi = (bh * 32 + w) * 768 + c;
        float r = val * 0.03125f + t[gi];
        t[gi] = r;
        t_h[gi] = (_Float16)r;
    }
}

// ---------------- spectral weight prep: [i][o] fp32 -> [o][i] f16, 128 matrices ----------------
// matrix id mid = ((d*2 + l)*2 + ri)*8 + n ; l: 0=w1 1=w2
__global__ __launch_bounds__(256) void prep_specw(const float* __restrict__ w1,
        const float* __restrict__ w2, _Float16* __restrict__ out)
{
    __shared__ float tile[96][97];
    int mid = blockIdx.x;
    int n  = mid & 7;
    int ri = (mid >> 3) & 1;
    int l  = (mid >> 4) & 1;
    int d  = mid >> 5;
    const float* src = (l ? w2 : w1) + ((size_t)(d * 2 + ri) * 8 + n) * 9216;
    for (int idx = threadIdx.x; idx < 9216; idx += 256)
        tile[idx / 96][idx % 96] = src[idx];
    __syncthreads();
    _Float16* dst = out + (size_t)mid * 9216;
    for (int idx = threadIdx.x; idx < 9216; idx += 256)
        dst[idx] = (_Float16)tile[idx % 96][idx / 96];   // dst[o][i] = src[i][o]
}

// ---------------- spectral block-diag complex MFMA layer ----------------
// out[pos, n*96+o] = act( XR@WR - XI@WI + bR , XI@WR + XR@WI + bI )
// grid (34, 8); 256 thr = 4 waves 2x2; wave tile M=32 x N=48; K=96 (3 chunks).
// IN_F16: input buffers f16, else fp32. ACT 0: gelu -> f16 out; ACT 1: shrink -> f32 out.
template<int IN_F16, int ACT>
__global__ __launch_bounds__(256) void spec_mfma(
        const void* __restrict__ inR_, const void* __restrict__ inI_,
        const _Float16* __restrict__ WtR, const _Float16* __restrict__ WtI,
        const float* __restrict__ bR, const float* __restrict__ bI,
        void* __restrict__ outR_, void* __restrict__ outI_)
{
    const int n   = blockIdx.y;
    const int m0  = blockIdx.x * 64;
    const int tid = threadIdx.x;
    const int wave = tid >> 6, lane = tid & 63;
    const int wr = wave >> 1, wc = wave & 1;
    const int lr = lane & 15, quad = lane >> 4;

    float4v accR[2][3], accI[2][3];
    #pragma unroll
    for (int i = 0; i < 2; ++i)
        #pragma unroll
        for (int j = 0; j < 3; ++j) {
            float4v z = {0.f, 0.f, 0.f, 0.f};
            accR[i][j] = z; accI[i][j] = z;
        }

    const _Float16* wRb = WtR + (size_t)n * 9216;
    const _Float16* wIb = WtI + (size_t)n * 9216;

    #pragma unroll
    for (int kc = 0; kc < 3; ++kc) {
        half8 aR[2], aI[2], aIn[2];
        #pragma unroll
        for (int i = 0; i < 2; ++i) {
            size_t off = (size_t)(m0 + wr * 32 + i * 16 + lr) * 768 + n * 96 + kc * 32 + quad * 8;
            if (IN_F16) {
                aR[i] = *(const half8*)((const _Float16*)inR_ + off);
                aI[i] = *(const half8*)((const _Float16*)inI_ + off);
            } else {
                aR[i] = ld_f32x8_as_h8((const float*)inR_ + off);
                aI[i] = ld_f32x8_as_h8((const float*)inI_ + off);
            }
            aIn[i] = -aI[i];
        }
        half8 bRf[3], bIf[3];
        #pragma unroll
        for (int j = 0; j < 3; ++j) {
            int o = wc * 48 + j * 16 + lr;
            bRf[j] = *(const half8*)&wRb[o * 96 + kc * 32 + quad * 8];
            bIf[j] = *(const half8*)&wIb[o * 96 + kc * 32 + quad * 8];
        }
        #pragma unroll
        for (int i = 0; i < 2; ++i)
            #pragma unroll
            for (int j = 0; j < 3; ++j) {
                accR[i][j] = __builtin_amdgcn_mfma_f32_16x16x32_f16(aR[i],  bRf[j], accR[i][j], 0, 0, 0);
                accR[i][j] = __builtin_amdgcn_mfma_f32_16x16x32_f16(aIn[i], bIf[j], accR[i][j], 0, 0, 0);
                accI[i][j] = __builtin_amdgcn_mfma_f32_16x16x32_f16(aI[i],  bRf[j], accI[i][j], 0, 0, 0);
                accI[i][j] = __builtin_amdgcn_mfma_f32_16x16x32_f16(aR[i],  bIf[j], accI[i][j], 0, 0, 0);
            }
    }

    #pragma unroll
    for (int j = 0; j < 3; ++j) {
        int ol = wc * 48 + j * 16 + lr;            // 0..95 within block n
        float br = bR[n * 96 + ol], bi = bI[n * 96 + ol];
        #pragma unroll
        for (int i = 0; i < 2; ++i) {
            int rowb = m0 + wr * 32 + i * 16 + quad * 4;
            #pragma unroll
            for (int r = 0; r < 4; ++r) {
                float vr = accR[i][j][r] + br;
                float vi = accI[i][j][r] + bi;
                size_t gi = (size_t)(rowb + r) * 768 + n * 96 + ol;
                if (ACT == 0) {
                    ((_Float16*)outR_)[gi] = (_Float16)gelu_f(vr);
                    ((_Float16*)outI_)[gi] = (_Float16)gelu_f(vi);
                } else {
                    ((float*)outR_)[gi] = shrink_f(vr);
                    ((float*)outI_)[gi] = shrink_f(vi);
                }
            }
        }
    }
}

// ---------------- f32 -> f16 elementwise (vectorized x4) ----------------
__global__ __launch_bounds__(256) void cvt_f16(const float* __restrict__ in,
        _Float16* __restrict__ out)
{
    int i = blockIdx.x * 256 + threadIdx.x;
    float4 v = ((const float4*)in)[i];
    half4v o;
    o.x = (_Float16)v.x; o.y = (_Float16)v.y; o.z = (_Float16)v.z; o.w = (_Float16)v.w;
    ((half4v*)out)[i] = o;
}

// ---------------- f32 [K][N] -> f16 [N][K] transpose ----------------
__global__ __launch_bounds__(256) void cvt_transpose(const float* __restrict__ in,
        _Float16* __restrict__ out, int K, int N)
{
    __shared__ float tile[32][33];
    int kb = blockIdx.x * 32, nb = blockIdx.y * 32;
    int tx = threadIdx.x & 31, ty = threadIdx.x >> 5;   // ty 0..7
    #pragma unroll
    for (int r = 0; r < 32; r += 8)
        tile[ty + r][tx] = in[(size_t)(kb + ty + r) * N + nb + tx];
    __syncthreads();
    #pragma unroll
    for (int r = 0; r < 32; r += 8)
        out[(size_t)(nb + ty + r) * K + kb + tx] = (_Float16)tile[tx][ty + r];
}

// ---------------- fp16 MFMA GEMM: C = act(A[M,K] @ Bt[N,K]^T + bias [+pos]) ----------------
// BM=128, BK=32, 256 threads = 4 waves (2x2), wave tile 64 x BN/2.
// OUT_MODE: 0 = f32, 1 = f16, 2 = dual (f32 + f16). pos: optional [1024][N] add (patch embed).
template<int BN, int OUT_MODE, int ACT>
__global__ __launch_bounds__(256) void gemm_h(const _Float16* __restrict__ A,
        const _Float16* __restrict__ Bt, const float* __restrict__ bias,
        const float* __restrict__ pos, float* __restrict__ C32,
        _Float16* __restrict__ C16, int M, int N, int K)
{
    constexpr int WN  = BN / 2;      // wave cols
    constexpr int FN  = WN / 16;     // col frags per wave
    constexpr int NBJ = BN / 64;     // B staging rounds
    __shared__ _Float16 Al[128 * 32];
    __shared__ _Float16 Bl[BN * 32];

    const int tid  = threadIdx.x;
    const int wave = tid >> 6;
    const int lane = tid & 63;
    const int wr   = wave >> 1;
    const int wc   = wave & 1;
    const int lr   = lane & 15;
    const int quad = lane >> 4;
    const int row0 = blockIdx.y * 128;
    const int col0 = blockIdx.x * BN;

    const int srow = lane >> 2;
    const int skof = (lane & 3) * 8;

    float4v acc[4][FN];
    #pragma unroll
    for (int i = 0; i < 4; ++i)
        #pragma unroll
        for (int j = 0; j < FN; ++j) {
            float4v z = {0.f, 0.f, 0.f, 0.f};
            acc[i][j] = z;
        }

    for (int k0 = 0; k0 < K; k0 += 32) {
        __syncthreads();
        #pragma unroll
        for (int j = 0; j < 2; ++j)
            async16(A + (size_t)(row0 + j * 64 + wave * 16 + srow) * K + k0 + skof,
                    &Al[(j * 64 + wave * 16) * 32]);
        #pragma unroll
        for (int j = 0; j < NBJ; ++j)
            async16(Bt + (size_t)(col0 + j * 64 + wave * 16 + srow) * K + k0 + skof,
                    &Bl[(j * 64 + wave * 16) * 32]);
        __syncthreads();

        half8 af[4], bf[FN];
        #pragma unroll
        for (int i = 0; i < 4; ++i)
            af[i] = *(const half8*)&Al[(wr * 64 + i * 16 + lr) * 32 + quad * 8];
        #pragma unroll
        for (int j = 0; j < FN; ++j)
            bf[j] = *(const half8*)&Bl[(wc * WN + j * 16 + lr) * 32 + quad * 8];
        #pragma unroll
        for (int i = 0; i < 4; ++i)
            #pragma unroll
            for (int j = 0; j < FN; ++j)
                acc[i][j] = __builtin_amdgcn_mfma_f32_16x16x32_f16(af[i], bf[j], acc[i][j], 0, 0, 0);
    }

    #pragma unroll
    for (int j = 0; j < FN; ++j) {
        int col = col0 + wc * WN + j * 16 + lr;
        float bj = bias[col];
        #pragma unroll
        for (int i = 0; i < 4; ++i) {
            int row = row0 + wr * 64 + i * 16 + quad * 4;
            #pragma unroll
            for (int r = 0; r < 4; ++r) {
                float v = acc[i][j][r] + bj;
                if (pos) v += pos[(size_t)((row + r) & 1023) * N + col];
                if (ACT) v = gelu_f(v);
                size_t gi = (size_t)(row + r) * N + col;
                if (OUT_MODE == 0 || OUT_MODE == 2) C32[gi] = v;
                if (OUT_MODE == 1 || OUT_MODE == 2) C16[gi] = (_Float16)v;
            }
        }
    }
}

// ---------------- head output scatter (pixel shuffle) ----------------
__global__ __launch_bounds__(256) void scatter_head(const float* __restrict__ h2,
        float* __restrict__ out, int f)
{
    int idx = blockIdx.x * 256 + threadIdx.x;     // 0 .. 262143
    int pq  = idx & 63;
    int tok = idx >> 6;
    int wp  = tok & 31;
    int hp  = (tok >> 5) & 31;
    int b   = tok >> 10;
    int p = pq >> 3, q = pq & 7;
    out[((b * 256 + hp * 8 + p) * 256 + wp * 8 + q) * 4 + f] = h2[idx];
}

// ---------------- launch ----------------
extern "C" void kernel_launch(void* const* d_in, const int* in_sizes, int n_in,
                              void* d_out, int out_size, void* d_ws, size_t ws_size,
                              hipStream_t stream) {
    const float* x        = (const float*)d_in[0];
    const float* grd      = (const float*)d_in[1];
    const float* conv_w   = (const float*)d_in[2];
    const float* conv_b   = (const float*)d_in[3];
    const float* pos_emb  = (const float*)d_in[4];
    const float* w1       = (const float*)d_in[5];
    const float* b1       = (const float*)d_in[6];
    const float* w2       = (const float*)d_in[7];
    const float* b2       = (const float*)d_in[8];
    const float* fc1_w    = (const float*)d_in[9];
    const float* fc1_b    = (const float*)d_in[10];
    const float* fc2_w    = (const float*)d_in[11];
    const float* fc2_b    = (const float*)d_in[12];
    const float* head_w1  = (const float*)d_in[13];
    const float* head_b1  = (const float*)d_in[14];
    const float* head_w2  = (const float*)d_in[15];
    const float* head_b2  = (const float*)d_in[16];
    float* out = (float*)d_out;
    float* ws  = (float*)d_ws;

    // ---- workspace layout (float units), total 22,331,392 f = 89.3 MB ----
    float* t    = ws;                        // 3,145,728
    float* xr   = t    + 3145728;            // 1,671,168
    float* xi   = xr   + 1671168;
    float* o1r  = xi   + 1671168;
    float* o1i  = o1r  + 1671168;
    float* h2   = o1i  + 1671168;            //   262,144
    float* pf   = h2   + 262144;
    _Float16* t_h    = (_Float16*)pf;  pf += 1572864;   // 4096x768 f16 (aliases A_h)
    _Float16* hid_h  = (_Float16*)pf;  pf += 6291456;   // 4096x3072 f16
    _Float16* convw_h= (_Float16*)pf;  pf += 294912;    // 768x768 f16
    _Float16* Wt     = (_Float16*)pf;  pf += 1179648;   // fc transpose scratch
    _Float16* Wsp    = (_Float16*)pf;  pf += 589824;    // spectral weights f16
    _Float16* hr_h   = (_Float16*)pf;  pf += 835584;    // 2176x768 f16
    _Float16* hi_h   = (_Float16*)pf;  pf += 835584;
    _Float16* h1t    = (_Float16*)pf;  pf += 589824;    // head_w1^T f16
    _Float16* h2t    = (_Float16*)pf;  pf += 49152;     // head_w2^T f16
    _Float16* A_h    = t_h;                             // prepass-only alias

    // ---- prepass: weight prep + patch embed (MFMA) ----
    prep_specw<<<dim3(128), 256, 0, stream>>>(w1, w2, Wsp);
    cvt_f16<<<dim3(576), 256, 0, stream>>>(conv_w, convw_h);
    cvt_transpose<<<dim3(24, 48), 256, 0, stream>>>(head_w1, h1t, 768, 1536);
    cvt_transpose<<<dim3(48, 2), 256, 0, stream>>>(head_w2, h2t, 1536, 64);
    gather_patch<<<dim3(12288), 256, 0, stream>>>(x, grd, A_h);
    gemm_h<128, 0, 0><<<dim3(6, 32), 256, 0, stream>>>(
        A_h, convw_h, conv_b, pos_emb, t, nullptr, 4096, 768, 768);

    for (int f = 0; f < 4; ++f) {
        for (int d = 0; d < 4; ++d) {
            // rfft2 (ortho, 1/32 folded into fwd-W pass)
            dft_fwd_w<<<dim3(128, 3), 256, 0, stream>>>(t, o1r, o1i);
            dft_h<0><<<dim3(68, 6), 128, 0, stream>>>(o1r, o1i, xr, xi);
            // block-diag complex MLP via MFMA
            spec_mfma<0, 0><<<dim3(34, 8), 256, 0, stream>>>(
                xr, xi,
                Wsp + (size_t)((d * 2 + 0) * 2 + 0) * 73728,
                Wsp + (size_t)((d * 2 + 0) * 2 + 1) * 73728,
                b1 + d * 1536, b1 + d * 1536 + 768, hr_h, hi_h);
            spec_mfma<1, 1><<<dim3(34, 8), 256, 0, stream>>>(
                hr_h, hi_h,
                Wsp + (size_t)((d * 2 + 1) * 2 + 0) * 73728,
                Wsp + (size_t)((d * 2 + 1) * 2 + 1) * 73728,
                b2 + d * 1536, b2 + d * 1536 + 768, xr, xi);
            // irfft2 + residual (dual fp32/f16 write)
            dft_h<1><<<dim3(68, 6), 128, 0, stream>>>(xr, xi, o1r, o1i);
            dft_inv_w<<<dim3(128, 3), 256, 0, stream>>>(o1r, o1i, t, t_h);
            // channel MLP 768 -> 3072 -> 768 via fp16 MFMA
            cvt_transpose<<<dim3(24, 96), 256, 0, stream>>>(fc1_w + (size_t)d * 2359296, Wt, 768, 3072);
            gemm_h<128, 1, 1><<<dim3(24, 32), 256, 0, stream>>>(
                t_h, Wt, fc1_b + d * 3072, nullptr, nullptr, hid_h, 4096, 3072, 768);
            cvt_transpose<<<dim3(96, 24), 256, 0, stream>>>(fc2_w + (size_t)d * 2359296, Wt, 3072, 768);
            gemm_h<64, 2, 0><<<dim3(12, 32), 256, 0, stream>>>(
                hid_h, Wt, fc2_b + d * 768, nullptr, t, t_h, 4096, 768, 3072);
        }
        // head on current state (t_h mirrors t)
        gemm_h<128, 1, 1><<<dim3(12, 32), 256, 0, stream>>>(
            t_h, h1t, head_b1, nullptr, nullptr, hid_h, 4096, 1536, 768);
        gemm_h<64, 0, 0><<<dim3(1, 32), 256, 0, stream>>>(
            hid_h, h2t, head_b2, nullptr, h2, nullptr, 4096, 64, 1536);
        scatter_head<<<dim3(1024), 256, 0, stream>>>(h2, out, f);
    }
}